// Round 6
// baseline (211.901 us; speedup 1.0000x reference)
//
#include <hip/hip_runtime.h>

// KvPageState fused, wave-per-2-rows, 2-launch, nontemporal both ways:
//   out[slot] <- (valid(inv[slot]) ? [new_k[t], new_v[t]] : kv_pages[slot])
//
// Shapes (fp32):
//   kv_pages    [1024, 64, 16, 128] -> 65536 slot-rows of 2048 floats (8 KiB)
//   new_k/new_v [8192, 8, 128]      -> per-token 1024 floats each
//   token_dests i32[8192], flat slot in [0, 65536), -1/OOB = drop
//
// inv (d_ws) is NOT initialized: entry inv[slot]=t accepted only if
// 0<=t<num_tokens AND dests[t]==slot (garbage-tolerant, race-free since
// dests are distinct).
//
// R5 post-mortem: nt stores confirmed (212->198); big kernel at ~85% of the
// 6.29 TB/s copy ceiling. This round: process TWO rows per iteration so 16
// loads are in flight before the 16-store drain (halves vmcnt drain
// boundaries, 2x per-wave MLP). Single diff vs R5.

typedef float f4 __attribute__((ext_vector_type(4)));

__global__ void inv_scatter_kernel(const int* __restrict__ dests, int num_tokens,
                                   int* __restrict__ inv, int num_slots) {
    const int t = blockIdx.x * blockDim.x + threadIdx.x;
    if (t >= num_tokens) return;
    const int d = dests[t];
    if (d >= 0 && d < num_slots) inv[d] = t;
}

__global__ void __launch_bounds__(256, 8)
fused_copy_scatter(const f4* __restrict__ kv_pages,
                   const f4* __restrict__ new_k,
                   const f4* __restrict__ new_v,
                   const int* __restrict__ inv,
                   const int* __restrict__ dests,
                   f4* __restrict__ out,
                   int num_slots, int num_tokens) {
    const int lane   = threadIdx.x & 63;
    const int wave   = blockIdx.x * (blockDim.x >> 6) + (threadIdx.x >> 6);
    const int nwaves = gridDim.x * (blockDim.x >> 6);   // 8192

    // Pair of rows per iteration: (slot, slot + nwaves), stepping 2*nwaves.
    int slot = wave;
    if (slot >= num_slots) return;

    // current pair's tokens (validated)
    int t0 = inv[slot];
    int td0 = (t0 >= 0 && t0 < num_tokens) ? dests[t0] : -1;
    int s1 = slot + nwaves;
    int t1 = (s1 < num_slots) ? inv[s1] : -1;
    int td1 = (t1 >= 0 && t1 < num_tokens) ? dests[t1] : -1;

    for (; slot < num_slots; slot += 2 * nwaves) {
        const int slot1 = slot + nwaves;

        // prefetch NEXT pair's (inv, dests)
        const int pn0 = slot + 2 * nwaves;
        const int pn1 = slot + 3 * nwaves;
        int tn0 = -1, tdn0 = -1, tn1 = -1, tdn1 = -1;
        if (pn0 < num_slots) {
            tn0 = inv[pn0];
            if (tn0 >= 0 && tn0 < num_tokens) tdn0 = dests[tn0];
        }
        if (pn1 < num_slots) {
            tn1 = inv[pn1];
            if (tn1 >= 0 && tn1 < num_tokens) tdn1 = dests[tn1];
        }

        // issue all 16 loads (8 per row) before any store
        f4 r0[8], r1[8];
        {
            const f4* src0 = (td0 == slot)
                ? nullptr : kv_pages + (size_t)slot * 512 + lane;
            if (td0 == slot) {
                const f4* k = new_k + (size_t)t0 * 256 + lane;
                const f4* v = new_v + (size_t)t0 * 256 + lane;
#pragma unroll
                for (int j = 0; j < 4; ++j) r0[j]     = __builtin_nontemporal_load(k + j * 64);
#pragma unroll
                for (int j = 0; j < 4; ++j) r0[4 + j] = __builtin_nontemporal_load(v + j * 64);
            } else {
#pragma unroll
                for (int j = 0; j < 8; ++j) r0[j] = __builtin_nontemporal_load(src0 + j * 64);
            }
        }
        const bool have1 = (slot1 < num_slots);
        if (have1) {
            if (td1 == slot1) {
                const f4* k = new_k + (size_t)t1 * 256 + lane;
                const f4* v = new_v + (size_t)t1 * 256 + lane;
#pragma unroll
                for (int j = 0; j < 4; ++j) r1[j]     = __builtin_nontemporal_load(k + j * 64);
#pragma unroll
                for (int j = 0; j < 4; ++j) r1[4 + j] = __builtin_nontemporal_load(v + j * 64);
            } else {
                const f4* src1 = kv_pages + (size_t)slot1 * 512 + lane;
#pragma unroll
                for (int j = 0; j < 8; ++j) r1[j] = __builtin_nontemporal_load(src1 + j * 64);
            }
        }

        // drain: 16 stores
        {
            f4* o0 = out + (size_t)slot * 512 + lane;
#pragma unroll
            for (int j = 0; j < 8; ++j) __builtin_nontemporal_store(r0[j], o0 + j * 64);
        }
        if (have1) {
            f4* o1 = out + (size_t)slot1 * 512 + lane;
#pragma unroll
            for (int j = 0; j < 8; ++j) __builtin_nontemporal_store(r1[j], o1 + j * 64);
        }

        t0 = tn0; td0 = tdn0; t1 = tn1; td1 = tdn1;
    }
}

// Fallback (ws too small): plain copy + overwrite scatter.
__global__ void kv_scatter_kernel(const f4* __restrict__ new_k,
                                  const f4* __restrict__ new_v,
                                  const int* __restrict__ dests,
                                  f4* __restrict__ out,
                                  int num_slots) {
    const int t = blockIdx.x;
    const int d = dests[t];
    if (d < 0 || d >= num_slots) return;
    const f4* k = new_k + (size_t)t * 256;
    const f4* v = new_v + (size_t)t * 256;
    f4* o = out + (size_t)d * 512;
    const int i = threadIdx.x;
    o[i]       = k[i];
    o[i + 256] = v[i];
}

extern "C" void kernel_launch(void* const* d_in, const int* in_sizes, int n_in,
                              void* d_out, int out_size, void* d_ws, size_t ws_size,
                              hipStream_t stream) {
    const float* kv_pages = (const float*)d_in[0];
    const float* new_k    = (const float*)d_in[1];
    const float* new_v    = (const float*)d_in[2];
    const int*   dests    = (const int*)d_in[3];

    const int num_tokens = in_sizes[3];                 // 8192
    const int row_floats = 2 * 8 * 128;                 // 2048
    const int num_slots  = out_size / row_floats;       // 65536

    if (ws_size >= (size_t)num_slots * sizeof(int)) {
        int* inv = (int*)d_ws;
        inv_scatter_kernel<<<(num_tokens + 255) / 256, 256, 0, stream>>>(
            dests, num_tokens, inv, num_slots);
        // 2048 blocks x 256 thr = 8192 waves, fully resident (8 blk/CU);
        // 65536/8192 = 8 rows per wave = 4 pair-iterations.
        fused_copy_scatter<<<2048, 256, 0, stream>>>(
            (const f4*)kv_pages, (const f4*)new_k, (const f4*)new_v,
            inv, dests, (f4*)d_out, num_slots, num_tokens);
    } else {
        hipMemcpyAsync(d_out, kv_pages, (size_t)out_size * sizeof(float),
                       hipMemcpyDeviceToDevice, stream);
        kv_scatter_kernel<<<num_tokens, 256, 0, stream>>>(
            (const f4*)new_k, (const f4*)new_v, dests, (f4*)d_out, num_slots);
    }
}

// Round 7
// 197.056 us; speedup vs baseline: 1.0753x; 1.0753x over previous
//
#include <hip/hip_runtime.h>

// KvPageState fused, wave-per-row, 2-launch, nontemporal both ways:
//   out[slot] <- (valid(inv[slot]) ? [new_k[t], new_v[t]] : kv_pages[slot])
//
// Shapes (fp32):
//   kv_pages    [1024, 64, 16, 128] -> 65536 slot-rows of 2048 floats (8 KiB)
//   new_k/new_v [8192, 8, 128]      -> per-token 1024 floats each
//   token_dests i32[8192], flat slot in [0, 65536), -1/OOB = drop
//
// inv (d_ws) is NOT initialized: entry inv[slot]=t is accepted only if
// 0<=t<num_tokens AND dests[t]==slot. Garbage either fails the check
// (-> copy kv_pages, correct) or names the one token genuinely targeting
// this slot (-> identical row). Distinct dests -> race-free.
//
// History: R4 regular stores 212us (L2 write-allocate contention) -> NT.
// R6 2-row batching 212us (launch_bounds(256,8) caps 64 VGPR; 16 f4 in
// flight spills to scratch) -> 1 row/iter. This is the R5 structure
// (198us, ~89% of the 6.29 TB/s measured copy ceiling at minimal traffic).

typedef float f4 __attribute__((ext_vector_type(4)));

__global__ void inv_scatter_kernel(const int* __restrict__ dests, int num_tokens,
                                   int* __restrict__ inv, int num_slots) {
    const int t = blockIdx.x * blockDim.x + threadIdx.x;
    if (t >= num_tokens) return;
    const int d = dests[t];
    if (d >= 0 && d < num_slots) inv[d] = t;
}

__global__ void __launch_bounds__(256, 8)
fused_copy_scatter(const f4* __restrict__ kv_pages,
                   const f4* __restrict__ new_k,
                   const f4* __restrict__ new_v,
                   const int* __restrict__ inv,
                   const int* __restrict__ dests,
                   f4* __restrict__ out,
                   int num_slots, int num_tokens) {
    const int lane   = threadIdx.x & 63;
    const int wave   = blockIdx.x * (blockDim.x >> 6) + (threadIdx.x >> 6);
    const int nwaves = gridDim.x * (blockDim.x >> 6);

    int slot = wave;
    if (slot >= num_slots) return;

    int t  = inv[slot];                                            // wave-uniform
    int td = (t >= 0 && t < num_tokens) ? dests[t] : -1;           // validate

    for (; slot < num_slots; slot += nwaves) {
        // prefetch next row's (inv, dests): chain hides under the copy
        const int nslot = slot + nwaves;
        int tn = -1, tdn = -1;
        if (nslot < num_slots) {
            tn = inv[nslot];
            if (tn >= 0 && tn < num_tokens) tdn = dests[tn];
        }

        f4* o = out + (size_t)slot * 512 + lane;
        if (td == slot) {                                          // fresh row
            const f4* k = new_k + (size_t)t * 256 + lane;
            const f4* v = new_v + (size_t)t * 256 + lane;
#pragma unroll
            for (int j = 0; j < 4; ++j)
                __builtin_nontemporal_store(__builtin_nontemporal_load(k + j * 64), o + j * 64);
#pragma unroll
            for (int j = 0; j < 4; ++j)
                __builtin_nontemporal_store(__builtin_nontemporal_load(v + j * 64), o + 256 + j * 64);
        } else {                                                   // keep row
            const f4* src = kv_pages + (size_t)slot * 512 + lane;
#pragma unroll
            for (int j = 0; j < 8; ++j)
                __builtin_nontemporal_store(__builtin_nontemporal_load(src + j * 64), o + j * 64);
        }
        t = tn; td = tdn;
    }
}

// Fallback (ws too small): plain copy + overwrite scatter.
__global__ void kv_scatter_kernel(const f4* __restrict__ new_k,
                                  const f4* __restrict__ new_v,
                                  const int* __restrict__ dests,
                                  f4* __restrict__ out,
                                  int num_slots) {
    const int t = blockIdx.x;
    const int d = dests[t];
    if (d < 0 || d >= num_slots) return;
    const f4* k = new_k + (size_t)t * 256;
    const f4* v = new_v + (size_t)t * 256;
    f4* o = out + (size_t)d * 512;
    const int i = threadIdx.x;
    o[i]       = k[i];
    o[i + 256] = v[i];
}

extern "C" void kernel_launch(void* const* d_in, const int* in_sizes, int n_in,
                              void* d_out, int out_size, void* d_ws, size_t ws_size,
                              hipStream_t stream) {
    const float* kv_pages = (const float*)d_in[0];
    const float* new_k    = (const float*)d_in[1];
    const float* new_v    = (const float*)d_in[2];
    const int*   dests    = (const int*)d_in[3];

    const int num_tokens = in_sizes[3];                 // 8192
    const int row_floats = 2 * 8 * 128;                 // 2048
    const int num_slots  = out_size / row_floats;       // 65536

    if (ws_size >= (size_t)num_slots * sizeof(int)) {
        int* inv = (int*)d_ws;
        inv_scatter_kernel<<<(num_tokens + 255) / 256, 256, 0, stream>>>(
            dests, num_tokens, inv, num_slots);
        // 2048 blocks x 256 thr = 8192 waves, fully resident (8 blk/CU);
        // 65536/8192 = 8 rows per wave.
        fused_copy_scatter<<<2048, 256, 0, stream>>>(
            (const f4*)kv_pages, (const f4*)new_k, (const f4*)new_v,
            inv, dests, (f4*)d_out, num_slots, num_tokens);
    } else {
        hipMemcpyAsync(d_out, kv_pages, (size_t)out_size * sizeof(float),
                       hipMemcpyDeviceToDevice, stream);
        kv_scatter_kernel<<<num_tokens, 256, 0, stream>>>(
            (const f4*)new_k, (const f4*)new_v, dests, (f4*)d_out, num_slots);
    }
}